// Round 2
// baseline (1615.130 us; speedup 1.0000x reference)
//
#include <hip/hip_runtime.h>
#include <hip/hip_bf16.h>
#include <cstdint>

#define BN_EPS 1e-5f

typedef __attribute__((ext_vector_type(8))) short short8;
typedef __attribute__((ext_vector_type(4))) short short4v;
typedef __attribute__((ext_vector_type(8))) __bf16 bf16x8;
typedef __attribute__((ext_vector_type(4))) float f32x4;

__device__ inline short f2bf(float f) {
    union { float f; unsigned u; } v; v.f = f;
    unsigned r = v.u + 0x7fffu + ((v.u >> 16) & 1u); // RNE
    return (short)(r >> 16);
}
__device__ inline float bf2f(short h) {
    union { unsigned u; float f; } v;
    v.u = ((unsigned)(unsigned short)h) << 16;
    return v.f;
}

// ---------------- setup kernels ----------------

__global__ void zero_kernel(float* stats, int nstats, int* deg, int N) {
    int i = blockIdx.x * 256 + threadIdx.x;
    if (i < nstats) stats[i] = 0.f;
    if (i < N) deg[i] = 0;
}

// transpose + bf16 split weights: WtHi/WtLo[mat][n][k] = split(W[mat][k][n])
__global__ void tw_kernel(const float* __restrict__ W1, const float* __restrict__ W2,
                          short* __restrict__ WtHi, short* __restrict__ WtLo) {
    int t = blockIdx.x * 256 + threadIdx.x;
    if (t >= 10 * 128 * 128) return;
    int mat = t >> 14, n = (t >> 7) & 127, k = t & 127;
    const float* W = (mat < 5) ? (W1 + mat * 16384) : (W2 + (mat - 5) * 16384);
    float w = W[k * 128 + n];
    short hi = f2bf(w);
    WtHi[t] = hi;
    WtLo[t] = f2bf(w - bf2f(hi));
}

__global__ void count_kernel(const int* __restrict__ dst, int* __restrict__ deg, int E) {
    int e = blockIdx.x * 256 + threadIdx.x;
    if (e < E) atomicAdd(&deg[dst[e]], 1);
}

__global__ __launch_bounds__(1024) void scan_kernel(const int* __restrict__ deg,
                                                    int* __restrict__ rowptr,
                                                    int* __restrict__ cursor, int N) {
    __shared__ int ps[1024];
    int t = threadIdx.x;
    int chunk = (N + 1023) >> 10;
    int s = t * chunk;
    int e = s + chunk; if (e > N) e = N; if (s > N) s = N;
    int local = 0;
    for (int i = s; i < e; ++i) local += deg[i];
    ps[t] = local;
    __syncthreads();
    for (int off = 1; off < 1024; off <<= 1) {
        int v = 0;
        if (t >= off) v = ps[t - off];
        __syncthreads();
        ps[t] += v;
        __syncthreads();
    }
    int run = ps[t] - local; // exclusive prefix
    for (int i = s; i < e; ++i) {
        rowptr[i] = run; cursor[i] = run;
        run += deg[i];
    }
    if (t == 1023) rowptr[N] = ps[1023];
}

__global__ void fill_kernel(const int* __restrict__ src, const int* __restrict__ dst,
                            int* __restrict__ cursor, int* __restrict__ colidx, int E) {
    int e = blockIdx.x * 256 + threadIdx.x;
    if (e < E) {
        int p = atomicAdd(&cursor[dst[e]], 1);
        colidx[p] = src[e];
    }
}

// ---------------- aggregation: rst[i] = f(y[i]) + sum_{j in in(i)} f(y[j]) ----------------
// f = identity (layer 0) or relu(a*x+c) from bn3 stats of previous layer.

__global__ __launch_bounds__(256) void agg_kernel(
    const float* __restrict__ Y, const int* __restrict__ rowptr,
    const int* __restrict__ colidx, const float* __restrict__ stats,
    const float* __restrict__ g, const float* __restrict__ bb,
    float* __restrict__ rst, int N, int useBN) {
    int node = (blockIdx.x * 256 + threadIdx.x) >> 6;
    if (node >= N) return;
    int lane = threadIdx.x & 63;
    float a0 = 1.f, c0 = 0.f, a1 = 1.f, c1 = 0.f;
    if (useBN) {
        float s = stats[lane], q = stats[128 + lane];
        float m = s / N, v = q / N - m * m;
        a0 = g[lane] * rsqrtf(v + BN_EPS);
        c0 = bb[lane] - m * a0;
        s = stats[64 + lane]; q = stats[192 + lane];
        m = s / N; v = q / N - m * m;
        a1 = g[64 + lane] * rsqrtf(v + BN_EPS);
        c1 = bb[64 + lane] - m * a1;
    }
    const float* yr = Y + (size_t)node * 128;
    float x0 = yr[lane], x1 = yr[64 + lane];
    float acc0 = useBN ? fmaxf(a0 * x0 + c0, 0.f) : x0;
    float acc1 = useBN ? fmaxf(a1 * x1 + c1, 0.f) : x1;
    int e = rowptr[node], end = rowptr[node + 1];
    for (; e < end; ++e) {
        int j = colidx[e];
        const float* yj = Y + (size_t)j * 128;
        float u0 = yj[lane], u1 = yj[64 + lane];
        acc0 += useBN ? fmaxf(a0 * u0 + c0, 0.f) : u0;
        acc1 += useBN ? fmaxf(a1 * u1 + c1, 0.f) : u1;
    }
    float* rr = rst + (size_t)node * 128;
    rr[lane] = acc0;
    rr[64 + lane] = acc1;
}

// ---------------- GEMM: C = pre(A) @ W + bias, accumulate column sum/sumsq of C ----------------
// Split precision: A = Ah + Al (bf16 pair, in LDS), W = Wh + Wl (bf16 pair, global).
// C ≈ Ah·Wh + Al·Wh + Ah·Wl  (drops Al·Wl ~ 2^-18 relative).
// pre: PRE==0 identity; PRE==1 relu(a*x+c) from preStats/preG/preB.

template <int PRE>
__global__ __launch_bounds__(256, 2) void gemm_kernel(
    const float* __restrict__ A,
    const short* __restrict__ WtHi, const short* __restrict__ WtLo,
    const float* __restrict__ bias,
    const float* __restrict__ preStats, const float* __restrict__ preG,
    const float* __restrict__ preB,
    float* __restrict__ C, float* __restrict__ outStats, int N) {
    __shared__ short AsHi[128 * 128];
    __shared__ short AsLo[128 * 128];

    const int t = threadIdx.x;
    const int row0 = blockIdx.x * 128;

    // per-thread BN params for its 4 staging columns
    float ta[4], tc[4];
    const int cc = (t & 31) * 4;
    if (PRE) {
#pragma unroll
        for (int k = 0; k < 4; ++k) {
            float s = preStats[cc + k], q = preStats[128 + cc + k];
            float m = s / N, v = q / N - m * m;
            ta[k] = preG[cc + k] * rsqrtf(v + BN_EPS);
            tc[k] = preB[cc + k] - m * ta[k];
        }
    }

    // stage A -> AsHi/AsLo (f32 -> bf16 split, optional BN+ReLU), XOR-swizzled rows
    const int r0 = t >> 5;
#pragma unroll
    for (int i = 0; i < 16; ++i) {
        int r = r0 + i * 8;
        int gr = row0 + r;
        float4 v = make_float4(0.f, 0.f, 0.f, 0.f);
        if (gr < N) v = *(const float4*)(A + (size_t)gr * 128 + cc);
        if (PRE) {
            v.x = fmaxf(ta[0] * v.x + tc[0], 0.f);
            v.y = fmaxf(ta[1] * v.y + tc[1], 0.f);
            v.z = fmaxf(ta[2] * v.z + tc[2], 0.f);
            v.w = fmaxf(ta[3] * v.w + tc[3], 0.f);
        }
        short4v hv, lv;
        hv.x = f2bf(v.x); lv.x = f2bf(v.x - bf2f(hv.x));
        hv.y = f2bf(v.y); lv.y = f2bf(v.y - bf2f(hv.y));
        hv.z = f2bf(v.z); lv.z = f2bf(v.z - bf2f(hv.z));
        hv.w = f2bf(v.w); lv.w = f2bf(v.w - bf2f(hv.w));
        int idx = r * 128 + (cc ^ ((r & 7) * 8));
        *(short4v*)(AsHi + idx) = hv;
        *(short4v*)(AsLo + idx) = lv;
    }
    __syncthreads();

    const int w = t >> 6, lane = t & 63;
    const int quad = lane >> 4, l16 = lane & 15;
    const int sw = (l16 & 7) * 8; // row&7 == l16&7 for all rows used below

    f32x4 acc[2][8];
#pragma unroll
    for (int m = 0; m < 2; ++m)
#pragma unroll
        for (int n = 0; n < 8; ++n) acc[m][n] = (f32x4){0.f, 0.f, 0.f, 0.f};

#pragma unroll
    for (int kk = 0; kk < 4; ++kk) {
        int kb = kk * 32 + quad * 8;
        int aoff0 = (w * 32 + l16) * 128 + (kb ^ sw);
        int aoff1 = (w * 32 + 16 + l16) * 128 + (kb ^ sw);
        bf16x8 a0h = __builtin_bit_cast(bf16x8, *(const short8*)(AsHi + aoff0));
        bf16x8 a1h = __builtin_bit_cast(bf16x8, *(const short8*)(AsHi + aoff1));
        bf16x8 a0l = __builtin_bit_cast(bf16x8, *(const short8*)(AsLo + aoff0));
        bf16x8 a1l = __builtin_bit_cast(bf16x8, *(const short8*)(AsLo + aoff1));
#pragma unroll
        for (int n = 0; n < 8; ++n) {
            int woff = (n * 16 + l16) * 128 + kb;
            bf16x8 bh = __builtin_bit_cast(bf16x8, *(const short8*)(WtHi + woff));
            bf16x8 bl = __builtin_bit_cast(bf16x8, *(const short8*)(WtLo + woff));
            acc[0][n] = __builtin_amdgcn_mfma_f32_16x16x32_bf16(a0h, bh, acc[0][n], 0, 0, 0);
            acc[0][n] = __builtin_amdgcn_mfma_f32_16x16x32_bf16(a0l, bh, acc[0][n], 0, 0, 0);
            acc[0][n] = __builtin_amdgcn_mfma_f32_16x16x32_bf16(a0h, bl, acc[0][n], 0, 0, 0);
            acc[1][n] = __builtin_amdgcn_mfma_f32_16x16x32_bf16(a1h, bh, acc[1][n], 0, 0, 0);
            acc[1][n] = __builtin_amdgcn_mfma_f32_16x16x32_bf16(a1l, bh, acc[1][n], 0, 0, 0);
            acc[1][n] = __builtin_amdgcn_mfma_f32_16x16x32_bf16(a1h, bl, acc[1][n], 0, 0, 0);
        }
    }

    // epilogue: bias add, store, column stats
    float bv[8];
#pragma unroll
    for (int n = 0; n < 8; ++n) bv[n] = bias[n * 16 + l16];
    float ls[8], lsq[8];
#pragma unroll
    for (int n = 0; n < 8; ++n) { ls[n] = 0.f; lsq[n] = 0.f; }
#pragma unroll
    for (int m = 0; m < 2; ++m) {
        int rbase = row0 + w * 32 + m * 16 + quad * 4;
#pragma unroll
        for (int n = 0; n < 8; ++n) {
            int colv = n * 16 + l16;
#pragma unroll
            for (int r = 0; r < 4; ++r) {
                int row = rbase + r;
                if (row < N) {
                    float val = acc[m][n][r] + bv[n];
                    C[(size_t)row * 128 + colv] = val;
                    ls[n] += val;
                    lsq[n] += val * val;
                }
            }
        }
    }
#pragma unroll
    for (int n = 0; n < 8; ++n) {
        float s = ls[n], q = lsq[n];
        s += __shfl_xor(s, 16, 64);
        s += __shfl_xor(s, 32, 64);
        q += __shfl_xor(q, 16, 64);
        q += __shfl_xor(q, 32, 64);
        if (quad == 0) {
            int colv = n * 16 + l16;
            atomicAdd(&outStats[colv], s);
            atomicAdd(&outStats[128 + colv], q);
        }
    }
}

// ---------------- elementwise y = relu(bn(x)), accumulate stats of y ----------------

__global__ __launch_bounds__(256) void elt_kernel(
    const float* __restrict__ X, const float* __restrict__ inStats,
    const float* __restrict__ g, const float* __restrict__ bb,
    float* __restrict__ Y, float* __restrict__ outStats, int N) {
    __shared__ float red[256 * 8];
    int t = threadIdx.x;
    int cg = t & 31;
    float a[4], c[4];
#pragma unroll
    for (int k = 0; k < 4; ++k) {
        int colv = cg * 4 + k;
        float s = inStats[colv], q = inStats[128 + colv];
        float m = s / N, v = q / N - m * m;
        a[k] = g[colv] * rsqrtf(v + BN_EPS);
        c[k] = bb[colv] - m * a[k];
    }
    float sum[4] = {0.f, 0.f, 0.f, 0.f}, sq[4] = {0.f, 0.f, 0.f, 0.f};
    int total = N * 32;
    for (int i = blockIdx.x * 256 + t; i < total; i += gridDim.x * 256) {
        float4 v = ((const float4*)X)[i];
        float4 y;
        y.x = fmaxf(a[0] * v.x + c[0], 0.f);
        y.y = fmaxf(a[1] * v.y + c[1], 0.f);
        y.z = fmaxf(a[2] * v.z + c[2], 0.f);
        y.w = fmaxf(a[3] * v.w + c[3], 0.f);
        ((float4*)Y)[i] = y;
        sum[0] += y.x; sq[0] += y.x * y.x;
        sum[1] += y.y; sq[1] += y.y * y.y;
        sum[2] += y.z; sq[2] += y.z * y.z;
        sum[3] += y.w; sq[3] += y.w * y.w;
    }
#pragma unroll
    for (int k = 0; k < 4; ++k) { red[t * 8 + k] = sum[k]; red[t * 8 + 4 + k] = sq[k]; }
    __syncthreads();
    if (t < 32) {
        float S[4] = {0.f, 0.f, 0.f, 0.f}, Q[4] = {0.f, 0.f, 0.f, 0.f};
        for (int j = 0; j < 8; ++j) {
            int tt = t + 32 * j;
#pragma unroll
            for (int k = 0; k < 4; ++k) { S[k] += red[tt * 8 + k]; Q[k] += red[tt * 8 + 4 + k]; }
        }
#pragma unroll
        for (int k = 0; k < 4; ++k) {
            atomicAdd(&outStats[t * 4 + k], S[k]);
            atomicAdd(&outStats[128 + t * 4 + k], Q[k]);
        }
    }
}

// ---------------- final: out = relu(bn3(y2)) ----------------

__global__ void final_kernel(const float* __restrict__ X, const float* __restrict__ inStats,
                             const float* __restrict__ g, const float* __restrict__ bb,
                             float* __restrict__ out, int N) {
    int i = blockIdx.x * 256 + threadIdx.x;
    int total = N * 32;
    if (i >= total) return;
    int cg = i & 31;
    float a[4], c[4];
#pragma unroll
    for (int k = 0; k < 4; ++k) {
        int colv = cg * 4 + k;
        float s = inStats[colv], q = inStats[128 + colv];
        float m = s / N, v = q / N - m * m;
        a[k] = g[colv] * rsqrtf(v + BN_EPS);
        c[k] = bb[colv] - m * a[k];
    }
    float4 v = ((const float4*)X)[i];
    float4 y;
    y.x = fmaxf(a[0] * v.x + c[0], 0.f);
    y.y = fmaxf(a[1] * v.y + c[1], 0.f);
    y.z = fmaxf(a[2] * v.z + c[2], 0.f);
    y.w = fmaxf(a[3] * v.w + c[3], 0.f);
    ((float4*)out)[i] = y;
}

// ---------------- launch ----------------

extern "C" void kernel_launch(void* const* d_in, const int* in_sizes, int n_in,
                              void* d_out, int out_size, void* d_ws, size_t ws_size,
                              hipStream_t stream) {
    const float* h0   = (const float*)d_in[0];
    const int*   src  = (const int*)d_in[1];
    const int*   dst  = (const int*)d_in[2];
    const float* W1   = (const float*)d_in[3];
    const float* b1   = (const float*)d_in[4];
    const float* W2   = (const float*)d_in[5];
    const float* b2   = (const float*)d_in[6];
    const float* bn1g = (const float*)d_in[7];
    const float* bn1b = (const float*)d_in[8];
    const float* bn2g = (const float*)d_in[9];
    const float* bn2b = (const float*)d_in[10];
    const float* bn3g = (const float*)d_in[11];
    const float* bn3b = (const float*)d_in[12];
    const int N = in_sizes[0] / 128;
    const int E = in_sizes[1];

    char* ws = (char*)d_ws;
    size_t off = 0;
    auto alloc = [&](size_t bytes) {
        void* p = ws + off;
        off = (off + bytes + 255) & ~(size_t)255;
        return p;
    };
    float* stats  = (float*)alloc(5 * 3 * 256 * sizeof(float)); // [l][which][sum:128|sumsq:128]
    int*   deg    = (int*)alloc((size_t)N * 4);
    int*   cursor = (int*)alloc((size_t)N * 4);
    int*   rowptr = (int*)alloc((size_t)(N + 1) * 4);
    int*   colidx = (int*)alloc((size_t)E * 4);
    short* WtHi   = (short*)alloc((size_t)10 * 16384 * 2);
    short* WtLo   = (short*)alloc((size_t)10 * 16384 * 2);
    float* buf0   = (float*)alloc((size_t)N * 128 * 4); // rst / x2
    float* buf1   = (float*)alloc((size_t)N * 128 * 4); // x1 / y2

    const int nstats = 5 * 3 * 256;
    int zgrid = ((N > nstats ? N : nstats) + 255) / 256;
    zero_kernel<<<zgrid, 256, 0, stream>>>(stats, nstats, deg, N);
    tw_kernel<<<(10 * 16384 + 255) / 256, 256, 0, stream>>>(W1, W2, WtHi, WtLo);
    count_kernel<<<(E + 255) / 256, 256, 0, stream>>>(dst, deg, E);
    scan_kernel<<<1, 1024, 0, stream>>>(deg, rowptr, cursor, N);
    fill_kernel<<<(E + 255) / 256, 256, 0, stream>>>(src, dst, cursor, colidx, E);

    const int gemmGrid = (N + 127) / 128;
    for (int l = 0; l < 5; ++l) {
        int lp = (l == 0) ? 0 : l - 1;
        agg_kernel<<<(N + 3) / 4, 256, 0, stream>>>(
            (l == 0) ? h0 : buf1, rowptr, colidx,
            stats + (lp * 3 + 2) * 256, bn3g + lp * 128, bn3b + lp * 128,
            buf0, N, l > 0 ? 1 : 0);
        gemm_kernel<0><<<gemmGrid, 256, 0, stream>>>(
            buf0, WtHi + l * 16384, WtLo + l * 16384, b1 + l * 128,
            nullptr, nullptr, nullptr,
            buf1, stats + (l * 3 + 0) * 256, N);
        gemm_kernel<1><<<gemmGrid, 256, 0, stream>>>(
            buf1, WtHi + (5 + l) * 16384, WtLo + (5 + l) * 16384, b2 + l * 128,
            stats + (l * 3 + 0) * 256, bn1g + l * 128, bn1b + l * 128,
            buf0, stats + (l * 3 + 1) * 256, N);
        elt_kernel<<<512, 256, 0, stream>>>(
            buf0, stats + (l * 3 + 1) * 256, bn2g + l * 128, bn2b + l * 128,
            buf1, stats + (l * 3 + 2) * 256, N);
    }
    final_kernel<<<(N * 32 + 255) / 256, 256, 0, stream>>>(
        buf1, stats + (4 * 3 + 2) * 256, bn3g + 4 * 128, bn3b + 4 * 128,
        (float*)d_out, N);
}

// Round 3
// 1502.639 us; speedup vs baseline: 1.0749x; 1.0749x over previous
//
#include <hip/hip_runtime.h>
#include <hip/hip_bf16.h>
#include <cstdint>

#define BN_EPS 1e-5f

typedef __attribute__((ext_vector_type(8))) short short8;
typedef __attribute__((ext_vector_type(4))) short short4v;
typedef __attribute__((ext_vector_type(8))) __bf16 bf16x8;
typedef __attribute__((ext_vector_type(4))) float f32x4;

__device__ inline short f2bf(float f) {
    union { float f; unsigned u; } v; v.f = f;
    unsigned r = v.u + 0x7fffu + ((v.u >> 16) & 1u); // RNE
    return (short)(r >> 16);
}
__device__ inline float bf2f(short h) {
    union { unsigned u; float f; } v;
    v.u = ((unsigned)(unsigned short)h) << 16;
    return v.f;
}

// ---------------- setup kernels ----------------

__global__ void zero_kernel(float* stats, int nstats, int* deg, int N) {
    int i = blockIdx.x * 256 + threadIdx.x;
    if (i < nstats) stats[i] = 0.f;
    if (i < N) deg[i] = 0;
}

// transpose + bf16 split weights: WtHi/WtLo[mat][n][k] = split(W[mat][k][n])
__global__ void tw_kernel(const float* __restrict__ W1, const float* __restrict__ W2,
                          short* __restrict__ WtHi, short* __restrict__ WtLo) {
    int t = blockIdx.x * 256 + threadIdx.x;
    if (t >= 10 * 128 * 128) return;
    int mat = t >> 14, n = (t >> 7) & 127, k = t & 127;
    const float* W = (mat < 5) ? (W1 + mat * 16384) : (W2 + (mat - 5) * 16384);
    float w = W[k * 128 + n];
    short hi = f2bf(w);
    WtHi[t] = hi;
    WtLo[t] = f2bf(w - bf2f(hi));
}

__global__ void count_kernel(const int* __restrict__ dst, int* __restrict__ deg, int E) {
    int e = blockIdx.x * 256 + threadIdx.x;
    if (e < E) atomicAdd(&deg[dst[e]], 1);
}

// ---- multi-block exclusive scan of deg -> rowptr/cursor (1024 elems per block) ----

__global__ __launch_bounds__(256) void scanA_kernel(const int* __restrict__ deg,
                                                    int* __restrict__ blockSums, int N) {
    int t = threadIdx.x, b = blockIdx.x;
    int base = b * 1024 + t * 4;
    int s = 0;
#pragma unroll
    for (int k = 0; k < 4; ++k) { int i = base + k; if (i < N) s += deg[i]; }
#pragma unroll
    for (int off = 1; off < 64; off <<= 1) s += __shfl_xor(s, off, 64);
    __shared__ int ws[4];
    if ((t & 63) == 0) ws[t >> 6] = s;
    __syncthreads();
    if (t == 0) blockSums[b] = ws[0] + ws[1] + ws[2] + ws[3];
}

// single block: exclusive-scan blockSums (nb <= 256), write total -> rowptrN
__global__ __launch_bounds__(256) void scanB_kernel(int* __restrict__ blockSums,
                                                    int* __restrict__ rowptrN, int nb) {
    __shared__ int ps[256];
    int t = threadIdx.x;
    int v = (t < nb) ? blockSums[t] : 0;
    ps[t] = v;
    __syncthreads();
#pragma unroll
    for (int off = 1; off < 256; off <<= 1) {
        int u = 0;
        if (t >= off) u = ps[t - off];
        __syncthreads();
        ps[t] += u;
        __syncthreads();
    }
    if (t < nb) blockSums[t] = ps[t] - v; // exclusive
    if (t == 255) rowptrN[0] = ps[255];   // grand total
}

__global__ __launch_bounds__(256) void scanC_kernel(const int* __restrict__ deg,
                                                    const int* __restrict__ blockSums,
                                                    int* __restrict__ rowptr,
                                                    int* __restrict__ cursor, int N) {
    __shared__ int ps[256];
    int t = threadIdx.x, b = blockIdx.x;
    int base = b * 1024 + t * 4;
    int d[4];
    int s = 0;
#pragma unroll
    for (int k = 0; k < 4; ++k) {
        d[k] = (base + k < N) ? deg[base + k] : 0;
        s += d[k];
    }
    int local = s;
    ps[t] = s;
    __syncthreads();
#pragma unroll
    for (int off = 1; off < 256; off <<= 1) {
        int u = 0;
        if (t >= off) u = ps[t - off];
        __syncthreads();
        ps[t] += u;
        __syncthreads();
    }
    int pre = ps[t] - local + blockSums[b];
#pragma unroll
    for (int k = 0; k < 4; ++k) {
        int i = base + k;
        if (i < N) { rowptr[i] = pre; cursor[i] = pre; pre += d[k]; }
    }
}

__global__ void fill_kernel(const int* __restrict__ src, const int* __restrict__ dst,
                            int* __restrict__ cursor, int* __restrict__ colidx, int E) {
    int e = blockIdx.x * 256 + threadIdx.x;
    if (e < E) {
        int p = atomicAdd(&cursor[dst[e]], 1);
        colidx[p] = src[e];
    }
}

// ---------------- aggregation: rst[i] = f(x[i]) + sum_{j in in(i)} f(x[j]) ----------------
// MODE 0: f = identity (layer 0, x = h0)
// MODE 1: f(u) = relu(a3*relu(a2*u+c2)+c3)  — composed bn2+relu, bn3+relu of prev layer

template <int MODE>
__global__ __launch_bounds__(256) void agg_kernel(
    const float* __restrict__ X, const int* __restrict__ rowptr,
    const int* __restrict__ colidx,
    const float* __restrict__ stats2, const float* __restrict__ g2, const float* __restrict__ b2v,
    const float* __restrict__ statsY, const float* __restrict__ g3, const float* __restrict__ b3v,
    float* __restrict__ rst, int N) {
    int node = (blockIdx.x * 256 + threadIdx.x) >> 6;
    if (node >= N) return;
    int lane = threadIdx.x & 63;
    float a2_0 = 1.f, c2_0 = 0.f, a2_1 = 1.f, c2_1 = 0.f;
    float a3_0 = 1.f, c3_0 = 0.f, a3_1 = 1.f, c3_1 = 0.f;
    if (MODE) {
        float s = stats2[lane], q = stats2[128 + lane];
        float m = s / N, v = q / N - m * m;
        a2_0 = g2[lane] * rsqrtf(v + BN_EPS);
        c2_0 = b2v[lane] - m * a2_0;
        s = stats2[64 + lane]; q = stats2[192 + lane];
        m = s / N; v = q / N - m * m;
        a2_1 = g2[64 + lane] * rsqrtf(v + BN_EPS);
        c2_1 = b2v[64 + lane] - m * a2_1;

        s = statsY[lane]; q = statsY[128 + lane];
        m = s / N; v = q / N - m * m;
        a3_0 = g3[lane] * rsqrtf(v + BN_EPS);
        c3_0 = b3v[lane] - m * a3_0;
        s = statsY[64 + lane]; q = statsY[192 + lane];
        m = s / N; v = q / N - m * m;
        a3_1 = g3[64 + lane] * rsqrtf(v + BN_EPS);
        c3_1 = b3v[64 + lane] - m * a3_1;
    }
    auto f0 = [&](float u) {
        if (MODE == 0) return u;
        float z = fmaxf(a2_0 * u + c2_0, 0.f);
        return fmaxf(a3_0 * z + c3_0, 0.f);
    };
    auto f1 = [&](float u) {
        if (MODE == 0) return u;
        float z = fmaxf(a2_1 * u + c2_1, 0.f);
        return fmaxf(a3_1 * z + c3_1, 0.f);
    };
    const float* xr = X + (size_t)node * 128;
    float acc0 = f0(xr[lane]);
    float acc1 = f1(xr[64 + lane]);
    int e = rowptr[node], end = rowptr[node + 1];
    for (; e < end; ++e) {
        int j = colidx[e];
        const float* xj = X + (size_t)j * 128;
        acc0 += f0(xj[lane]);
        acc1 += f1(xj[64 + lane]);
    }
    float* rr = rst + (size_t)node * 128;
    rr[lane] = acc0;
    rr[64 + lane] = acc1;
}

// ---------------- GEMM: C = pre(A) @ W + bias, accumulate column sum/sumsq of C ----------------
// Split precision: A = Ah + Al (bf16 pair, in LDS), W = Wh + Wl (bf16 pair, global).
// C ≈ Ah·Wh + Al·Wh + Ah·Wl  (drops Al·Wl ~ 2^-18 relative).
// pre: PRE==0 identity; PRE==1 relu(a*x+c) from preStats/preG/preB.

template <int PRE>
__global__ __launch_bounds__(256, 2) void gemm_kernel(
    const float* __restrict__ A,
    const short* __restrict__ WtHi, const short* __restrict__ WtLo,
    const float* __restrict__ bias,
    const float* __restrict__ preStats, const float* __restrict__ preG,
    const float* __restrict__ preB,
    float* __restrict__ C, float* __restrict__ outStats, int N) {
    __shared__ short AsHi[128 * 128];
    __shared__ short AsLo[128 * 128];

    const int t = threadIdx.x;
    const int row0 = blockIdx.x * 128;

    float ta[4], tc[4];
    const int cc = (t & 31) * 4;
    if (PRE) {
#pragma unroll
        for (int k = 0; k < 4; ++k) {
            float s = preStats[cc + k], q = preStats[128 + cc + k];
            float m = s / N, v = q / N - m * m;
            ta[k] = preG[cc + k] * rsqrtf(v + BN_EPS);
            tc[k] = preB[cc + k] - m * ta[k];
        }
    }

    const int r0 = t >> 5;
#pragma unroll
    for (int i = 0; i < 16; ++i) {
        int r = r0 + i * 8;
        int gr = row0 + r;
        float4 v = make_float4(0.f, 0.f, 0.f, 0.f);
        if (gr < N) v = *(const float4*)(A + (size_t)gr * 128 + cc);
        if (PRE) {
            v.x = fmaxf(ta[0] * v.x + tc[0], 0.f);
            v.y = fmaxf(ta[1] * v.y + tc[1], 0.f);
            v.z = fmaxf(ta[2] * v.z + tc[2], 0.f);
            v.w = fmaxf(ta[3] * v.w + tc[3], 0.f);
        }
        short4v hv, lv;
        hv.x = f2bf(v.x); lv.x = f2bf(v.x - bf2f(hv.x));
        hv.y = f2bf(v.y); lv.y = f2bf(v.y - bf2f(hv.y));
        hv.z = f2bf(v.z); lv.z = f2bf(v.z - bf2f(hv.z));
        hv.w = f2bf(v.w); lv.w = f2bf(v.w - bf2f(hv.w));
        int idx = r * 128 + (cc ^ ((r & 7) * 8));
        *(short4v*)(AsHi + idx) = hv;
        *(short4v*)(AsLo + idx) = lv;
    }
    __syncthreads();

    const int w = t >> 6, lane = t & 63;
    const int quad = lane >> 4, l16 = lane & 15;
    const int sw = (l16 & 7) * 8;

    f32x4 acc[2][8];
#pragma unroll
    for (int m = 0; m < 2; ++m)
#pragma unroll
        for (int n = 0; n < 8; ++n) acc[m][n] = (f32x4){0.f, 0.f, 0.f, 0.f};

#pragma unroll
    for (int kk = 0; kk < 4; ++kk) {
        int kb = kk * 32 + quad * 8;
        int aoff0 = (w * 32 + l16) * 128 + (kb ^ sw);
        int aoff1 = (w * 32 + 16 + l16) * 128 + (kb ^ sw);
        bf16x8 a0h = __builtin_bit_cast(bf16x8, *(const short8*)(AsHi + aoff0));
        bf16x8 a1h = __builtin_bit_cast(bf16x8, *(const short8*)(AsHi + aoff1));
        bf16x8 a0l = __builtin_bit_cast(bf16x8, *(const short8*)(AsLo + aoff0));
        bf16x8 a1l = __builtin_bit_cast(bf16x8, *(const short8*)(AsLo + aoff1));
#pragma unroll
        for (int n = 0; n < 8; ++n) {
            int woff = (n * 16 + l16) * 128 + kb;
            bf16x8 bh = __builtin_bit_cast(bf16x8, *(const short8*)(WtHi + woff));
            bf16x8 bl = __builtin_bit_cast(bf16x8, *(const short8*)(WtLo + woff));
            acc[0][n] = __builtin_amdgcn_mfma_f32_16x16x32_bf16(a0h, bh, acc[0][n], 0, 0, 0);
            acc[0][n] = __builtin_amdgcn_mfma_f32_16x16x32_bf16(a0l, bh, acc[0][n], 0, 0, 0);
            acc[0][n] = __builtin_amdgcn_mfma_f32_16x16x32_bf16(a0h, bl, acc[0][n], 0, 0, 0);
            acc[1][n] = __builtin_amdgcn_mfma_f32_16x16x32_bf16(a1h, bh, acc[1][n], 0, 0, 0);
            acc[1][n] = __builtin_amdgcn_mfma_f32_16x16x32_bf16(a1l, bh, acc[1][n], 0, 0, 0);
            acc[1][n] = __builtin_amdgcn_mfma_f32_16x16x32_bf16(a1h, bl, acc[1][n], 0, 0, 0);
        }
    }

    float bv[8];
#pragma unroll
    for (int n = 0; n < 8; ++n) bv[n] = bias[n * 16 + l16];
    float ls[8], lsq[8];
#pragma unroll
    for (int n = 0; n < 8; ++n) { ls[n] = 0.f; lsq[n] = 0.f; }
#pragma unroll
    for (int m = 0; m < 2; ++m) {
        int rbase = row0 + w * 32 + m * 16 + quad * 4;
#pragma unroll
        for (int n = 0; n < 8; ++n) {
            int colv = n * 16 + l16;
#pragma unroll
            for (int r = 0; r < 4; ++r) {
                int row = rbase + r;
                if (row < N) {
                    float val = acc[m][n][r] + bv[n];
                    C[(size_t)row * 128 + colv] = val;
                    ls[n] += val;
                    lsq[n] += val * val;
                }
            }
        }
    }
#pragma unroll
    for (int n = 0; n < 8; ++n) {
        float s = ls[n], q = lsq[n];
        s += __shfl_xor(s, 16, 64);
        s += __shfl_xor(s, 32, 64);
        q += __shfl_xor(q, 16, 64);
        q += __shfl_xor(q, 32, 64);
        if (quad == 0) {
            int colv = n * 16 + l16;
            atomicAdd(&outStats[colv], s);
            atomicAdd(&outStats[128 + colv], q);
        }
    }
}

// ---------------- stats of y = relu(bn(x)) (no materialization) ----------------

__global__ __launch_bounds__(256) void elt_kernel(
    const float* __restrict__ X, const float* __restrict__ inStats,
    const float* __restrict__ g, const float* __restrict__ bb,
    float* __restrict__ outStats, int N) {
    __shared__ float red[256 * 8];
    int t = threadIdx.x;
    int cg = t & 31;
    float a[4], c[4];
#pragma unroll
    for (int k = 0; k < 4; ++k) {
        int colv = cg * 4 + k;
        float s = inStats[colv], q = inStats[128 + colv];
        float m = s / N, v = q / N - m * m;
        a[k] = g[colv] * rsqrtf(v + BN_EPS);
        c[k] = bb[colv] - m * a[k];
    }
    float sum[4] = {0.f, 0.f, 0.f, 0.f}, sq[4] = {0.f, 0.f, 0.f, 0.f};
    int total = N * 32;
    for (int i = blockIdx.x * 256 + t; i < total; i += gridDim.x * 256) {
        float4 v = ((const float4*)X)[i];
        float4 y;
        y.x = fmaxf(a[0] * v.x + c[0], 0.f);
        y.y = fmaxf(a[1] * v.y + c[1], 0.f);
        y.z = fmaxf(a[2] * v.z + c[2], 0.f);
        y.w = fmaxf(a[3] * v.w + c[3], 0.f);
        sum[0] += y.x; sq[0] += y.x * y.x;
        sum[1] += y.y; sq[1] += y.y * y.y;
        sum[2] += y.z; sq[2] += y.z * y.z;
        sum[3] += y.w; sq[3] += y.w * y.w;
    }
#pragma unroll
    for (int k = 0; k < 4; ++k) { red[t * 8 + k] = sum[k]; red[t * 8 + 4 + k] = sq[k]; }
    __syncthreads();
    if (t < 32) {
        float S[4] = {0.f, 0.f, 0.f, 0.f}, Q[4] = {0.f, 0.f, 0.f, 0.f};
        for (int j = 0; j < 8; ++j) {
            int tt = t + 32 * j;
#pragma unroll
            for (int k = 0; k < 4; ++k) { S[k] += red[tt * 8 + k]; Q[k] += red[tt * 8 + 4 + k]; }
        }
#pragma unroll
        for (int k = 0; k < 4; ++k) {
            atomicAdd(&outStats[t * 4 + k], S[k]);
            atomicAdd(&outStats[128 + t * 4 + k], Q[k]);
        }
    }
}

// ---------------- final: out = relu(bn3(relu(bn2(x2)))) ----------------

__global__ void final_kernel(const float* __restrict__ X,
                             const float* __restrict__ stats2, const float* __restrict__ g2,
                             const float* __restrict__ b2v,
                             const float* __restrict__ statsY, const float* __restrict__ g3,
                             const float* __restrict__ b3v,
                             float* __restrict__ out, int N) {
    int i = blockIdx.x * 256 + threadIdx.x;
    int total = N * 32;
    if (i >= total) return;
    int cg = i & 31;
    float a2[4], c2[4], a3[4], c3[4];
#pragma unroll
    for (int k = 0; k < 4; ++k) {
        int colv = cg * 4 + k;
        float s = stats2[colv], q = stats2[128 + colv];
        float m = s / N, v = q / N - m * m;
        a2[k] = g2[colv] * rsqrtf(v + BN_EPS);
        c2[k] = b2v[colv] - m * a2[k];
        s = statsY[colv]; q = statsY[128 + colv];
        m = s / N; v = q / N - m * m;
        a3[k] = g3[colv] * rsqrtf(v + BN_EPS);
        c3[k] = b3v[colv] - m * a3[k];
    }
    float4 v = ((const float4*)X)[i];
    float4 y;
    y.x = fmaxf(a3[0] * fmaxf(a2[0] * v.x + c2[0], 0.f) + c3[0], 0.f);
    y.y = fmaxf(a3[1] * fmaxf(a2[1] * v.y + c2[1], 0.f) + c3[1], 0.f);
    y.z = fmaxf(a3[2] * fmaxf(a2[2] * v.z + c2[2], 0.f) + c3[2], 0.f);
    y.w = fmaxf(a3[3] * fmaxf(a2[3] * v.w + c2[3], 0.f) + c3[3], 0.f);
    ((float4*)out)[i] = y;
}

// ---------------- launch ----------------

extern "C" void kernel_launch(void* const* d_in, const int* in_sizes, int n_in,
                              void* d_out, int out_size, void* d_ws, size_t ws_size,
                              hipStream_t stream) {
    const float* h0   = (const float*)d_in[0];
    const int*   src  = (const int*)d_in[1];
    const int*   dst  = (const int*)d_in[2];
    const float* W1   = (const float*)d_in[3];
    const float* b1   = (const float*)d_in[4];
    const float* W2   = (const float*)d_in[5];
    const float* b2   = (const float*)d_in[6];
    const float* bn1g = (const float*)d_in[7];
    const float* bn1b = (const float*)d_in[8];
    const float* bn2g = (const float*)d_in[9];
    const float* bn2b = (const float*)d_in[10];
    const float* bn3g = (const float*)d_in[11];
    const float* bn3b = (const float*)d_in[12];
    const int N = in_sizes[0] / 128;
    const int E = in_sizes[1];

    char* ws = (char*)d_ws;
    size_t off = 0;
    auto alloc = [&](size_t bytes) {
        void* p = ws + off;
        off = (off + bytes + 255) & ~(size_t)255;
        return p;
    };
    float* stats   = (float*)alloc(5 * 3 * 256 * sizeof(float)); // [l][which][sum:128|sumsq:128]
    int*   deg     = (int*)alloc((size_t)N * 4);
    int*   cursor  = (int*)alloc((size_t)N * 4);
    int*   rowptr  = (int*)alloc((size_t)(N + 1) * 4);
    int*   colidx  = (int*)alloc((size_t)E * 4);
    int*   bsums   = (int*)alloc(1024);
    short* WtHi    = (short*)alloc((size_t)10 * 16384 * 2);
    short* WtLo    = (short*)alloc((size_t)10 * 16384 * 2);
    float* buf0    = (float*)alloc((size_t)N * 128 * 4);
    float* buf1    = (float*)alloc((size_t)N * 128 * 4);

    const int nstats = 5 * 3 * 256;
    int zgrid = ((N > nstats ? N : nstats) + 255) / 256;
    zero_kernel<<<zgrid, 256, 0, stream>>>(stats, nstats, deg, N);
    tw_kernel<<<(10 * 16384 + 255) / 256, 256, 0, stream>>>(W1, W2, WtHi, WtLo);
    count_kernel<<<(E + 255) / 256, 256, 0, stream>>>(dst, deg, E);
    int nb = (N + 1023) / 1024;
    scanA_kernel<<<nb, 256, 0, stream>>>(deg, bsums, N);
    scanB_kernel<<<1, 256, 0, stream>>>(bsums, rowptr + N, nb);
    scanC_kernel<<<nb, 256, 0, stream>>>(deg, bsums, rowptr, cursor, N);
    fill_kernel<<<(E + 255) / 256, 256, 0, stream>>>(src, dst, cursor, colidx, E);

    const int gemmGrid = (N + 127) / 128;
    for (int l = 0; l < 5; ++l) {
        float* rstBuf = (l % 2 == 0) ? buf0 : buf1;
        float* x1Buf  = (l % 2 == 0) ? buf1 : buf0;
        float* x2Buf  = rstBuf;
        if (l == 0) {
            agg_kernel<0><<<(N + 3) / 4, 256, 0, stream>>>(
                h0, rowptr, colidx,
                nullptr, nullptr, nullptr, nullptr, nullptr, nullptr,
                rstBuf, N);
        } else {
            int lp = l - 1;
            const float* prevX2 = (lp % 2 == 0) ? buf0 : buf1;
            agg_kernel<1><<<(N + 3) / 4, 256, 0, stream>>>(
                prevX2, rowptr, colidx,
                stats + (lp * 3 + 1) * 256, bn2g + lp * 128, bn2b + lp * 128,
                stats + (lp * 3 + 2) * 256, bn3g + lp * 128, bn3b + lp * 128,
                rstBuf, N);
        }
        gemm_kernel<0><<<gemmGrid, 256, 0, stream>>>(
            rstBuf, WtHi + l * 16384, WtLo + l * 16384, b1 + l * 128,
            nullptr, nullptr, nullptr,
            x1Buf, stats + (l * 3 + 0) * 256, N);
        gemm_kernel<1><<<gemmGrid, 256, 0, stream>>>(
            x1Buf, WtHi + (5 + l) * 16384, WtLo + (5 + l) * 16384, b2 + l * 128,
            stats + (l * 3 + 0) * 256, bn1g + l * 128, bn1b + l * 128,
            x2Buf, stats + (l * 3 + 1) * 256, N);
        elt_kernel<<<512, 256, 0, stream>>>(
            x2Buf, stats + (l * 3 + 1) * 256, bn2g + l * 128, bn2b + l * 128,
            stats + (l * 3 + 2) * 256, N);
    }
    final_kernel<<<(N * 32 + 255) / 256, 256, 0, stream>>>(
        buf0,
        stats + (4 * 3 + 1) * 256, bn2g + 4 * 128, bn2b + 4 * 128,
        stats + (4 * 3 + 2) * 256, bn3g + 4 * 128, bn3b + 4 * 128,
        (float*)d_out, N);
}

// Round 4
// 749.336 us; speedup vs baseline: 2.1554x; 2.0053x over previous
//
#include <hip/hip_runtime.h>
#include <hip/hip_bf16.h>
#include <cstdint>

#define BN_EPS 1e-5f

typedef __attribute__((ext_vector_type(8))) short short8;
typedef __attribute__((ext_vector_type(8))) __bf16 bf16x8;
typedef __attribute__((ext_vector_type(4))) float f32x4;

__device__ inline short f2bf(float f) {
    union { float f; unsigned u; } v; v.f = f;
    unsigned r = v.u + 0x7fffu + ((v.u >> 16) & 1u); // RNE
    return (short)(r >> 16);
}
__device__ inline float bf2f(short h) {
    union { unsigned u; float f; } v;
    v.u = ((unsigned)(unsigned short)h) << 16;
    return v.f;
}

// ---------------- setup kernels ----------------

__global__ void zero_kernel(float* stats, int nstats, int* deg, int N) {
    int i = blockIdx.x * 256 + threadIdx.x;
    if (i < nstats) stats[i] = 0.f;
    if (i < N) deg[i] = 0;
}

// transpose + bf16 split weights: WtHi/WtLo[mat][n][k] = split(W[mat][k][n])
__global__ void tw_kernel(const float* __restrict__ W1, const float* __restrict__ W2,
                          short* __restrict__ WtHi, short* __restrict__ WtLo) {
    int t = blockIdx.x * 256 + threadIdx.x;
    if (t >= 10 * 128 * 128) return;
    int mat = t >> 14, n = (t >> 7) & 127, k = t & 127;
    const float* W = (mat < 5) ? (W1 + mat * 16384) : (W2 + (mat - 5) * 16384);
    float w = W[k * 128 + n];
    short hi = f2bf(w);
    WtHi[t] = hi;
    WtLo[t] = f2bf(w - bf2f(hi));
}

__global__ void count_kernel(const int* __restrict__ dst, int* __restrict__ deg, int E) {
    int e = blockIdx.x * 256 + threadIdx.x;
    if (e < E) atomicAdd(&deg[dst[e]], 1);
}

// ---- multi-block exclusive scan of deg -> rowptr/cursor ----

__global__ __launch_bounds__(256) void scanA_kernel(const int* __restrict__ deg,
                                                    int* __restrict__ blockSums, int N) {
    int t = threadIdx.x, b = blockIdx.x;
    int base = b * 1024 + t * 4;
    int s = 0;
#pragma unroll
    for (int k = 0; k < 4; ++k) { int i = base + k; if (i < N) s += deg[i]; }
#pragma unroll
    for (int off = 1; off < 64; off <<= 1) s += __shfl_xor(s, off, 64);
    __shared__ int ws[4];
    if ((t & 63) == 0) ws[t >> 6] = s;
    __syncthreads();
    if (t == 0) blockSums[b] = ws[0] + ws[1] + ws[2] + ws[3];
}

__global__ __launch_bounds__(256) void scanB_kernel(int* __restrict__ blockSums,
                                                    int* __restrict__ rowptrN, int nb) {
    __shared__ int ps[256];
    int t = threadIdx.x;
    int v = (t < nb) ? blockSums[t] : 0;
    ps[t] = v;
    __syncthreads();
#pragma unroll
    for (int off = 1; off < 256; off <<= 1) {
        int u = 0;
        if (t >= off) u = ps[t - off];
        __syncthreads();
        ps[t] += u;
        __syncthreads();
    }
    if (t < nb) blockSums[t] = ps[t] - v;
    if (t == 255) rowptrN[0] = ps[255];
}

__global__ __launch_bounds__(256) void scanC_kernel(const int* __restrict__ deg,
                                                    const int* __restrict__ blockSums,
                                                    int* __restrict__ rowptr,
                                                    int* __restrict__ cursor, int N) {
    __shared__ int ps[256];
    int t = threadIdx.x, b = blockIdx.x;
    int base = b * 1024 + t * 4;
    int d[4];
    int s = 0;
#pragma unroll
    for (int k = 0; k < 4; ++k) {
        d[k] = (base + k < N) ? deg[base + k] : 0;
        s += d[k];
    }
    int local = s;
    ps[t] = s;
    __syncthreads();
#pragma unroll
    for (int off = 1; off < 256; off <<= 1) {
        int u = 0;
        if (t >= off) u = ps[t - off];
        __syncthreads();
        ps[t] += u;
        __syncthreads();
    }
    int pre = ps[t] - local + blockSums[b];
#pragma unroll
    for (int k = 0; k < 4; ++k) {
        int i = base + k;
        if (i < N) { rowptr[i] = pre; cursor[i] = pre; pre += d[k]; }
    }
}

__global__ void fill_kernel(const int* __restrict__ src, const int* __restrict__ dst,
                            int* __restrict__ cursor, int* __restrict__ colidx, int E) {
    int e = blockIdx.x * 256 + threadIdx.x;
    if (e < E) {
        int p = atomicAdd(&cursor[dst[e]], 1);
        colidx[p] = src[e];
    }
}

// ---------------- coeff: stripes [8][256] -> a[128], c[128] ----------------

__global__ __launch_bounds__(128) void coeff_kernel(const float* __restrict__ stats,
                                                    const float* __restrict__ g,
                                                    const float* __restrict__ bb,
                                                    float* __restrict__ outAC, int N) {
    int col = threadIdx.x;
    float s = 0.f, q = 0.f;
#pragma unroll
    for (int st = 0; st < 8; ++st) {
        s += stats[st * 256 + col];
        q += stats[st * 256 + 128 + col];
    }
    float m = s / N, v = q / N - m * m;
    float a = g[col] * rsqrtf(v + BN_EPS);
    outAC[col] = a;
    outAC[128 + col] = bb[col] - m * a;
}

// ---------------- aggregation: rst[i] = f(x[i]) + sum_{j in in(i)} f(x[j]) ----------------
// MODE 0: f = identity (layer 0). MODE 1: f(u) = relu(a3*relu(a2*u+c2)+c3).
// One wave per node; lane handles columns 2*lane, 2*lane+1 (float2). Edge loop unrolled x4.

template <int MODE>
__global__ __launch_bounds__(256) void agg_kernel(
    const float* __restrict__ Xf, const int* __restrict__ rowptr,
    const int* __restrict__ colidx,
    const float* __restrict__ coeff2, const float* __restrict__ coeff3,
    float* __restrict__ rst, int N) {
    int node = (blockIdx.x * 256 + threadIdx.x) >> 6;
    if (node >= N) return;
    int lane = threadIdx.x & 63;
    int c0 = lane * 2, c1 = c0 + 1;
    float a2x = 1.f, c2x = 0.f, a2y = 1.f, c2y = 0.f;
    float a3x = 1.f, c3x = 0.f, a3y = 1.f, c3y = 0.f;
    if (MODE) {
        a2x = coeff2[c0]; a2y = coeff2[c1]; c2x = coeff2[128 + c0]; c2y = coeff2[128 + c1];
        a3x = coeff3[c0]; a3y = coeff3[c1]; c3x = coeff3[128 + c0]; c3y = coeff3[128 + c1];
    }
    auto fx = [&](float u) {
        if (MODE == 0) return u;
        float z = fmaxf(a2x * u + c2x, 0.f);
        return fmaxf(a3x * z + c3x, 0.f);
    };
    auto fy = [&](float u) {
        if (MODE == 0) return u;
        float z = fmaxf(a2y * u + c2y, 0.f);
        return fmaxf(a3y * z + c3y, 0.f);
    };
    const float2* X2 = (const float2*)Xf;
    float2 self = X2[(size_t)node * 64 + lane];
    float ax = fx(self.x), ay = fy(self.y);
    int e = rowptr[node], end = rowptr[node + 1];
    for (; e + 4 <= end; e += 4) {
        int j0 = colidx[e], j1 = colidx[e + 1], j2 = colidx[e + 2], j3 = colidx[e + 3];
        float2 v0 = X2[(size_t)j0 * 64 + lane];
        float2 v1 = X2[(size_t)j1 * 64 + lane];
        float2 v2 = X2[(size_t)j2 * 64 + lane];
        float2 v3 = X2[(size_t)j3 * 64 + lane];
        ax += fx(v0.x) + fx(v1.x) + fx(v2.x) + fx(v3.x);
        ay += fy(v0.y) + fy(v1.y) + fy(v2.y) + fy(v3.y);
    }
    for (; e < end; ++e) {
        int j = colidx[e];
        float2 v = X2[(size_t)j * 64 + lane];
        ax += fx(v.x);
        ay += fy(v.y);
    }
    float2 r; r.x = ax; r.y = ay;
    ((float2*)rst)[(size_t)node * 64 + lane] = r;
}

// ---------------- GEMM: C = pre(A) @ W + bias, striped column stats ----------------
// W hi/lo staged in LDS (XOR-swizzled); A streamed global->registers with split conversion.
// pre (PRE==1): relu(a*x+c) with a,c from precomputed coeff table preAC (a[128], c[128]).

template <int PRE>
__global__ __launch_bounds__(256, 2) void gemm_kernel(
    const float* __restrict__ A,
    const short* __restrict__ WtHi, const short* __restrict__ WtLo,
    const float* __restrict__ bias,
    const float* __restrict__ preAC,
    float* __restrict__ C, float* __restrict__ outStats, int N) {
    __shared__ short WsHi[128 * 128];
    __shared__ short WsLo[128 * 128];

    const int t = threadIdx.x;
    const int row0 = blockIdx.x * 128;
    const int w = t >> 6, lane = t & 63;
    const int quad = lane >> 4, l16 = lane & 15;
    const int sw = (l16 & 7) * 8;

    // phase 1: A f32 loads (rows w*32+l16, w*32+16+l16)
    float4 af[2][4][2];
#pragma unroll
    for (int m = 0; m < 2; ++m) {
        int gr = row0 + w * 32 + m * 16 + l16;
        bool ok = gr < N;
        const float* Ar = A + (size_t)gr * 128;
#pragma unroll
        for (int kk = 0; kk < 4; ++kk) {
            int kb = kk * 32 + quad * 8;
            af[m][kk][0] = ok ? *(const float4*)(Ar + kb) : make_float4(0.f, 0.f, 0.f, 0.f);
            af[m][kk][1] = ok ? *(const float4*)(Ar + kb + 4) : make_float4(0.f, 0.f, 0.f, 0.f);
        }
    }

    // phase 2: stage W hi/lo into LDS, XOR-swizzled rows
#pragma unroll
    for (int i = 0; i < 8; ++i) {
        int ch = t + i * 256;
        int r = ch >> 4, k = (ch & 15) * 8;
        int d = r * 128 + (k ^ ((r & 7) * 8));
        *(short8*)(WsHi + d) = *(const short8*)(WtHi + r * 128 + k);
        *(short8*)(WsLo + d) = *(const short8*)(WtLo + r * 128 + k);
    }

    // phase 3: BN + split-convert A fragments
    short8 fh[2][4], fl[2][4];
#pragma unroll
    for (int kk = 0; kk < 4; ++kk) {
        int kb = kk * 32 + quad * 8;
        float a8[8], c8[8];
        if (PRE) {
            *(float4*)(a8) = *(const float4*)(preAC + kb);
            *(float4*)(a8 + 4) = *(const float4*)(preAC + kb + 4);
            *(float4*)(c8) = *(const float4*)(preAC + 128 + kb);
            *(float4*)(c8 + 4) = *(const float4*)(preAC + 128 + kb + 4);
        }
#pragma unroll
        for (int m = 0; m < 2; ++m) {
            float x[8];
            *(float4*)(x) = af[m][kk][0];
            *(float4*)(x + 4) = af[m][kk][1];
            short8 h, lo;
#pragma unroll
            for (int j = 0; j < 8; ++j) {
                float y = PRE ? fmaxf(a8[j] * x[j] + c8[j], 0.f) : x[j];
                short hi = f2bf(y);
                h[j] = hi;
                lo[j] = f2bf(y - bf2f(hi));
            }
            fh[m][kk] = h;
            fl[m][kk] = lo;
        }
    }
    __syncthreads();

    f32x4 acc[2][8];
#pragma unroll
    for (int m = 0; m < 2; ++m)
#pragma unroll
        for (int n = 0; n < 8; ++n) acc[m][n] = (f32x4){0.f, 0.f, 0.f, 0.f};

#pragma unroll
    for (int kk = 0; kk < 4; ++kk) {
        int kb = kk * 32 + quad * 8;
        bf16x8 a0h = __builtin_bit_cast(bf16x8, fh[0][kk]);
        bf16x8 a1h = __builtin_bit_cast(bf16x8, fh[1][kk]);
        bf16x8 a0l = __builtin_bit_cast(bf16x8, fl[0][kk]);
        bf16x8 a1l = __builtin_bit_cast(bf16x8, fl[1][kk]);
#pragma unroll
        for (int n = 0; n < 8; ++n) {
            int woff = (n * 16 + l16) * 128 + (kb ^ sw);
            bf16x8 bh = __builtin_bit_cast(bf16x8, *(const short8*)(WsHi + woff));
            bf16x8 bl = __builtin_bit_cast(bf16x8, *(const short8*)(WsLo + woff));
            acc[0][n] = __builtin_amdgcn_mfma_f32_16x16x32_bf16(a0h, bh, acc[0][n], 0, 0, 0);
            acc[0][n] = __builtin_amdgcn_mfma_f32_16x16x32_bf16(a0l, bh, acc[0][n], 0, 0, 0);
            acc[0][n] = __builtin_amdgcn_mfma_f32_16x16x32_bf16(a0h, bl, acc[0][n], 0, 0, 0);
            acc[1][n] = __builtin_amdgcn_mfma_f32_16x16x32_bf16(a1h, bh, acc[1][n], 0, 0, 0);
            acc[1][n] = __builtin_amdgcn_mfma_f32_16x16x32_bf16(a1l, bh, acc[1][n], 0, 0, 0);
            acc[1][n] = __builtin_amdgcn_mfma_f32_16x16x32_bf16(a1h, bl, acc[1][n], 0, 0, 0);
        }
    }

    __syncthreads(); // all LDS reads done; Ws memory reused below for stats reduction

    // epilogue: bias add, store C, per-wave column partials
    float bv[8];
#pragma unroll
    for (int n = 0; n < 8; ++n) bv[n] = bias[n * 16 + l16];
    float ls[8], lsq[8];
#pragma unroll
    for (int n = 0; n < 8; ++n) { ls[n] = 0.f; lsq[n] = 0.f; }
#pragma unroll
    for (int m = 0; m < 2; ++m) {
        int rbase = row0 + w * 32 + m * 16 + quad * 4;
#pragma unroll
        for (int n = 0; n < 8; ++n) {
            int colv = n * 16 + l16;
#pragma unroll
            for (int r = 0; r < 4; ++r) {
                int row = rbase + r;
                if (row < N) {
                    float val = acc[m][n][r] + bv[n];
                    C[(size_t)row * 128 + colv] = val;
                    ls[n] += val;
                    lsq[n] += val * val;
                }
            }
        }
    }

    float* P = (float*)WsHi; // reuse: [w][sum:256|sq interleaved] -> w*512 + {col, 256+col}
#pragma unroll
    for (int n = 0; n < 8; ++n) {
        float s = ls[n], q = lsq[n];
        s += __shfl_xor(s, 16, 64);
        s += __shfl_xor(s, 32, 64);
        q += __shfl_xor(q, 16, 64);
        q += __shfl_xor(q, 32, 64);
        if (quad == 0) {
            int colv = n * 16 + l16;
            P[w * 512 + colv] = s;
            P[w * 512 + 256 + colv] = q;
        }
    }
    __syncthreads();

    int stripe = blockIdx.x & 7;
    if (t < 128) {
        int col = t;
        float S = P[col] + P[512 + col] + P[1024 + col] + P[1536 + col];
        atomicAdd(&outStats[stripe * 256 + col], S);
    } else {
        int col = t - 128;
        float Q = P[256 + col] + P[768 + col] + P[1280 + col] + P[1792 + col];
        atomicAdd(&outStats[stripe * 256 + 128 + col], Q);
    }
}

// ---------------- stats of y = relu(a*x+c) (no materialization), striped ----------------

__global__ __launch_bounds__(256) void elt_kernel(
    const float* __restrict__ X, const float* __restrict__ coeffAC,
    float* __restrict__ outStats, int N) {
    __shared__ float red[256 * 8];
    int t = threadIdx.x;
    int cg = t & 31;
    float a[4], c[4];
#pragma unroll
    for (int k = 0; k < 4; ++k) {
        int colv = cg * 4 + k;
        a[k] = coeffAC[colv];
        c[k] = coeffAC[128 + colv];
    }
    float sum[4] = {0.f, 0.f, 0.f, 0.f}, sq[4] = {0.f, 0.f, 0.f, 0.f};
    int total = N * 32;
    for (int i = blockIdx.x * 256 + t; i < total; i += gridDim.x * 256) {
        float4 v = ((const float4*)X)[i];
        float4 y;
        y.x = fmaxf(a[0] * v.x + c[0], 0.f);
        y.y = fmaxf(a[1] * v.y + c[1], 0.f);
        y.z = fmaxf(a[2] * v.z + c[2], 0.f);
        y.w = fmaxf(a[3] * v.w + c[3], 0.f);
        sum[0] += y.x; sq[0] += y.x * y.x;
        sum[1] += y.y; sq[1] += y.y * y.y;
        sum[2] += y.z; sq[2] += y.z * y.z;
        sum[3] += y.w; sq[3] += y.w * y.w;
    }
#pragma unroll
    for (int k = 0; k < 4; ++k) { red[t * 8 + k] = sum[k]; red[t * 8 + 4 + k] = sq[k]; }
    __syncthreads();
    if (t < 32) {
        float S[4] = {0.f, 0.f, 0.f, 0.f}, Q[4] = {0.f, 0.f, 0.f, 0.f};
        for (int j = 0; j < 8; ++j) {
            int tt = t + 32 * j;
#pragma unroll
            for (int k = 0; k < 4; ++k) { S[k] += red[tt * 8 + k]; Q[k] += red[tt * 8 + 4 + k]; }
        }
        int stripe = blockIdx.x & 7;
#pragma unroll
        for (int k = 0; k < 4; ++k) {
            atomicAdd(&outStats[stripe * 256 + t * 4 + k], S[k]);
            atomicAdd(&outStats[stripe * 256 + 128 + t * 4 + k], Q[k]);
        }
    }
}

// ---------------- final: out = relu(a3*relu(a2*x+c2)+c3) ----------------

__global__ void final_kernel(const float* __restrict__ X,
                             const float* __restrict__ coeff2, const float* __restrict__ coeff3,
                             float* __restrict__ out, int N) {
    int i = blockIdx.x * 256 + threadIdx.x;
    int total = N * 32;
    if (i >= total) return;
    int cg = i & 31;
    float a2[4], c2[4], a3[4], c3[4];
#pragma unroll
    for (int k = 0; k < 4; ++k) {
        int colv = cg * 4 + k;
        a2[k] = coeff2[colv];
        c2[k] = coeff2[128 + colv];
        a3[k] = coeff3[colv];
        c3[k] = coeff3[128 + colv];
    }
    float4 v = ((const float4*)X)[i];
    float4 y;
    y.x = fmaxf(a3[0] * fmaxf(a2[0] * v.x + c2[0], 0.f) + c3[0], 0.f);
    y.y = fmaxf(a3[1] * fmaxf(a2[1] * v.y + c2[1], 0.f) + c3[1], 0.f);
    y.z = fmaxf(a3[2] * fmaxf(a2[2] * v.z + c2[2], 0.f) + c3[2], 0.f);
    y.w = fmaxf(a3[3] * fmaxf(a2[3] * v.w + c2[3], 0.f) + c3[3], 0.f);
    ((float4*)out)[i] = y;
}

// ---------------- launch ----------------

extern "C" void kernel_launch(void* const* d_in, const int* in_sizes, int n_in,
                              void* d_out, int out_size, void* d_ws, size_t ws_size,
                              hipStream_t stream) {
    const float* h0   = (const float*)d_in[0];
    const int*   src  = (const int*)d_in[1];
    const int*   dst  = (const int*)d_in[2];
    const float* W1   = (const float*)d_in[3];
    const float* b1   = (const float*)d_in[4];
    const float* W2   = (const float*)d_in[5];
    const float* b2   = (const float*)d_in[6];
    const float* bn1g = (const float*)d_in[7];
    const float* bn1b = (const float*)d_in[8];
    const float* bn2g = (const float*)d_in[9];
    const float* bn2b = (const float*)d_in[10];
    const float* bn3g = (const float*)d_in[11];
    const float* bn3b = (const float*)d_in[12];
    const int N = in_sizes[0] / 128;
    const int E = in_sizes[1];

    char* ws = (char*)d_ws;
    size_t off = 0;
    auto alloc = [&](size_t bytes) {
        void* p = ws + off;
        off = (off + bytes + 255) & ~(size_t)255;
        return p;
    };
    float* stats   = (float*)alloc((size_t)5 * 3 * 8 * 256 * sizeof(float)); // striped
    float* coeff   = (float*)alloc((size_t)5 * 3 * 256 * sizeof(float));     // a[128],c[128]
    int*   deg     = (int*)alloc((size_t)N * 4);
    int*   cursor  = (int*)alloc((size_t)N * 4);
    int*   rowptr  = (int*)alloc((size_t)(N + 1) * 4);
    int*   colidx  = (int*)alloc((size_t)E * 4);
    int*   bsums   = (int*)alloc(1024);
    short* WtHi    = (short*)alloc((size_t)10 * 16384 * 2);
    short* WtLo    = (short*)alloc((size_t)10 * 16384 * 2);
    float* buf0    = (float*)alloc((size_t)N * 128 * 4);
    float* buf1    = (float*)alloc((size_t)N * 128 * 4);

    auto statsBase = [&](int l, int which) { return stats + ((size_t)(l * 3 + which)) * 8 * 256; };
    auto coeffBase = [&](int l, int which) { return coeff + ((size_t)(l * 3 + which)) * 256; };

    const int nstats = 5 * 3 * 8 * 256;
    int zgrid = ((N > nstats ? N : nstats) + 255) / 256;
    zero_kernel<<<zgrid, 256, 0, stream>>>(stats, nstats, deg, N);
    tw_kernel<<<(10 * 16384 + 255) / 256, 256, 0, stream>>>(W1, W2, WtHi, WtLo);
    count_kernel<<<(E + 255) / 256, 256, 0, stream>>>(dst, deg, E);
    int nb = (N + 1023) / 1024;
    scanA_kernel<<<nb, 256, 0, stream>>>(deg, bsums, N);
    scanB_kernel<<<1, 256, 0, stream>>>(bsums, rowptr + N, nb);
    scanC_kernel<<<nb, 256, 0, stream>>>(deg, bsums, rowptr, cursor, N);
    fill_kernel<<<(E + 255) / 256, 256, 0, stream>>>(src, dst, cursor, colidx, E);

    const int gemmGrid = (N + 127) / 128;
    for (int l = 0; l < 5; ++l) {
        float* rstBuf = (l % 2 == 0) ? buf0 : buf1;
        float* x1Buf  = (l % 2 == 0) ? buf1 : buf0;
        float* x2Buf  = rstBuf;
        if (l == 0) {
            agg_kernel<0><<<(N + 3) / 4, 256, 0, stream>>>(
                h0, rowptr, colidx, nullptr, nullptr, rstBuf, N);
        } else {
            int lp = l - 1;
            const float* prevX2 = (lp % 2 == 0) ? buf0 : buf1;
            agg_kernel<1><<<(N + 3) / 4, 256, 0, stream>>>(
                prevX2, rowptr, colidx,
                coeffBase(lp, 1), coeffBase(lp, 2), rstBuf, N);
        }
        gemm_kernel<0><<<gemmGrid, 256, 0, stream>>>(
            rstBuf, WtHi + l * 16384, WtLo + l * 16384, b1 + l * 128,
            nullptr, x1Buf, statsBase(l, 0), N);
        coeff_kernel<<<1, 128, 0, stream>>>(statsBase(l, 0), bn1g + l * 128, bn1b + l * 128,
                                            coeffBase(l, 0), N);
        gemm_kernel<1><<<gemmGrid, 256, 0, stream>>>(
            x1Buf, WtHi + (5 + l) * 16384, WtLo + (5 + l) * 16384, b2 + l * 128,
            coeffBase(l, 0), x2Buf, statsBase(l, 1), N);
        coeff_kernel<<<1, 128, 0, stream>>>(statsBase(l, 1), bn2g + l * 128, bn2b + l * 128,
                                            coeffBase(l, 1), N);
        elt_kernel<<<256, 256, 0, stream>>>(
            x2Buf, coeffBase(l, 1), statsBase(l, 2), N);
        coeff_kernel<<<1, 128, 0, stream>>>(statsBase(l, 2), bn3g + l * 128, bn3b + l * 128,
                                            coeffBase(l, 2), N);
    }
    final_kernel<<<(N * 32 + 255) / 256, 256, 0, stream>>>(
        buf0, coeffBase(4, 1), coeffBase(4, 2), (float*)d_out, N);
}